// Round 10
// baseline (788.714 us; speedup 1.0000x reference)
//
#include <hip/hip_runtime.h>
#include <math.h>

#define NB 16
#define PP 1024
#define DD 64
#define MAX_ITER 10

constexpr float EPSV    = 0.1f;
constexpr float SCALE_G = 20.0f;     // 2/eps
constexpr float LOG2E   = 1.44269504088896340736f;
constexpr float LOG_MU  = -6.93146156597137f;   // log(1/1024 + 1e-8)
constexpr float THRESHV = 0.1f;

typedef short bf16x8 __attribute__((ext_vector_type(8)));
typedef float f32x16 __attribute__((ext_vector_type(16)));

__device__ __forceinline__ unsigned short f2bf(float f) {
  unsigned int u = __float_as_uint(f);
  return (unsigned short)((u + 0x7FFFu + ((u >> 16) & 1u)) >> 16);   // RNE
}
__device__ __forceinline__ float bf2f(unsigned short h) {
  return __uint_as_float(((unsigned int)h) << 16);
}

// ---------------------------------------------------------------------------
// Prep (validated r8): bf16 hi/lo split + scaled row norms 10*|r|^2.
// ---------------------------------------------------------------------------
__global__ __launch_bounds__(256) void prep_kernel(
    const float* __restrict__ x, const float* __restrict__ y,
    unsigned short* __restrict__ xh, unsigned short* __restrict__ xl,
    unsigned short* __restrict__ yh, unsigned short* __restrict__ yl,
    float* __restrict__ nxs, float* __restrict__ nys)
{
  const int sel = blockIdx.x >> 9;
  const int row = (blockIdx.x & 511) * 32 + (threadIdx.x >> 3);
  const int q   = threadIdx.x & 7;

  const float* src = sel ? y : x;
  unsigned short* H = sel ? yh : xh;
  unsigned short* L = sel ? yl : xl;
  float* N          = sel ? nys : nxs;

  const float* p = src + (size_t)row * DD + q * 8;
  float4 v0 = *(const float4*)(p);
  float4 v1 = *(const float4*)(p + 4);

  float f[8] = {v0.x, v0.y, v0.z, v0.w, v1.x, v1.y, v1.z, v1.w};
  float nrm = 0.f;
  unsigned short hb[8], lb[8];
  #pragma unroll
  for (int k = 0; k < 8; ++k) {
    nrm = fmaf(f[k], f[k], nrm);
    unsigned short h = f2bf(f[k]);
    float res = f[k] - bf2f(h);
    hb[k] = h; lb[k] = f2bf(res);
  }
  nrm += __shfl_xor(nrm, 1);
  nrm += __shfl_xor(nrm, 2);
  nrm += __shfl_xor(nrm, 4);
  if (q == 0) N[row] = 10.0f * nrm;

  uint4 ho, lo;
  ho.x = hb[0] | ((unsigned)hb[1] << 16); ho.y = hb[2] | ((unsigned)hb[3] << 16);
  ho.z = hb[4] | ((unsigned)hb[5] << 16); ho.w = hb[6] | ((unsigned)hb[7] << 16);
  lo.x = lb[0] | ((unsigned)lb[1] << 16); lo.y = lb[2] | ((unsigned)lb[3] << 16);
  lo.z = lb[4] | ((unsigned)lb[5] << 16); lo.w = lb[6] | ((unsigned)lb[7] << 16);
  *(uint4*)(H + (size_t)row * DD + q * 8) = ho;
  *(uint4*)(L + (size_t)row * DD + q * 8) = lo;
}

// ---------------------------------------------------------------------------
// Cs = nxs_i + nys_j - 20*<x_i,y_j> via split-bf16 MFMA (validated r8).
// ---------------------------------------------------------------------------
__global__ __launch_bounds__(256) void compute_c_mfma(
    const unsigned short* __restrict__ xh, const unsigned short* __restrict__ xl,
    const float* __restrict__ nxs,
    const unsigned short* __restrict__ yh, const unsigned short* __restrict__ yl,
    const float* __restrict__ nys,
    float* __restrict__ Cs)
{
  const int n   = blockIdx.x >> 8;
  const int ib  = (blockIdx.x >> 4) & 15;
  const int jb  = blockIdx.x & 15;
  const int tid = threadIdx.x;
  const int l   = tid & 63;
  const int w   = tid >> 6;
  const int ih  = w & 1, jh = w >> 1;

  __shared__ float nxv[64];
  if (tid < 64) nxv[tid] = nxs[n * PP + ib * 64 + tid];
  __syncthreads();

  const int jg  = n * PP + jb * 64 + 32 * jh + (l & 31);
  const float nyv = nys[jg];

  const int ko = 8 * (l >> 5);
  const size_t xrow = ((size_t)(n * PP + ib * 64 + 32 * ih + (l & 31))) * DD;
  const size_t yrow = ((size_t)jg) * DD;

  bf16x8 Xh0 = *(const bf16x8*)(xh + xrow + 0 * 16 + ko);
  bf16x8 Xh1 = *(const bf16x8*)(xh + xrow + 1 * 16 + ko);
  bf16x8 Xh2 = *(const bf16x8*)(xh + xrow + 2 * 16 + ko);
  bf16x8 Xh3 = *(const bf16x8*)(xh + xrow + 3 * 16 + ko);
  bf16x8 Xl0 = *(const bf16x8*)(xl + xrow + 0 * 16 + ko);
  bf16x8 Xl1 = *(const bf16x8*)(xl + xrow + 1 * 16 + ko);
  bf16x8 Xl2 = *(const bf16x8*)(xl + xrow + 2 * 16 + ko);
  bf16x8 Xl3 = *(const bf16x8*)(xl + xrow + 3 * 16 + ko);
  bf16x8 Yh0 = *(const bf16x8*)(yh + yrow + 0 * 16 + ko);
  bf16x8 Yh1 = *(const bf16x8*)(yh + yrow + 1 * 16 + ko);
  bf16x8 Yh2 = *(const bf16x8*)(yh + yrow + 2 * 16 + ko);
  bf16x8 Yh3 = *(const bf16x8*)(yh + yrow + 3 * 16 + ko);
  bf16x8 Yl0 = *(const bf16x8*)(yl + yrow + 0 * 16 + ko);
  bf16x8 Yl1 = *(const bf16x8*)(yl + yrow + 1 * 16 + ko);
  bf16x8 Yl2 = *(const bf16x8*)(yl + yrow + 2 * 16 + ko);
  bf16x8 Yl3 = *(const bf16x8*)(yl + yrow + 3 * 16 + ko);

  f32x16 acc;
  #pragma unroll
  for (int z = 0; z < 16; ++z) acc[z] = 0.f;
  acc = __builtin_amdgcn_mfma_f32_32x32x16_bf16(Xh0, Yh0, acc, 0, 0, 0);
  acc = __builtin_amdgcn_mfma_f32_32x32x16_bf16(Xh1, Yh1, acc, 0, 0, 0);
  acc = __builtin_amdgcn_mfma_f32_32x32x16_bf16(Xh2, Yh2, acc, 0, 0, 0);
  acc = __builtin_amdgcn_mfma_f32_32x32x16_bf16(Xh3, Yh3, acc, 0, 0, 0);
  acc = __builtin_amdgcn_mfma_f32_32x32x16_bf16(Xh0, Yl0, acc, 0, 0, 0);
  acc = __builtin_amdgcn_mfma_f32_32x32x16_bf16(Xh1, Yl1, acc, 0, 0, 0);
  acc = __builtin_amdgcn_mfma_f32_32x32x16_bf16(Xh2, Yl2, acc, 0, 0, 0);
  acc = __builtin_amdgcn_mfma_f32_32x32x16_bf16(Xh3, Yl3, acc, 0, 0, 0);
  acc = __builtin_amdgcn_mfma_f32_32x32x16_bf16(Xl0, Yh0, acc, 0, 0, 0);
  acc = __builtin_amdgcn_mfma_f32_32x32x16_bf16(Xl1, Yh1, acc, 0, 0, 0);
  acc = __builtin_amdgcn_mfma_f32_32x32x16_bf16(Xl2, Yh2, acc, 0, 0, 0);
  acc = __builtin_amdgcn_mfma_f32_32x32x16_bf16(Xl3, Yh3, acc, 0, 0, 0);

  const int irb  = 32 * ih + 4 * (l >> 5);
  const int jcol = jb * 64 + 32 * jh + (l & 31);
  #pragma unroll
  for (int r = 0; r < 16; ++r) {
    const int irel = irb + (r & 3) + 8 * (r >> 2);
    const size_t off = ((size_t)(n * PP + ib * 64 + irel)) * PP + jcol;
    Cs[off] = nxv[irel] + nyv - SCALE_G * acc[r];
  }
}

// ---------------------------------------------------------------------------
// u_mfma (UNDER TEST): a_i = LOG_MU + nxs_i - lse_j(bt_j + 20<y_j, x_i>),
// bt_j = b_j - nys_j. TWO-SWEEP: sweep1 block-max per col; sweep2 exp-sum.
// No online rescale. Grid 512 = 16 n x 32 itiles. arg0 = y (reduce side):
// per-lane D col = output i (l&31), rows = j-subset (validated layout).
// ---------------------------------------------------------------------------
__global__ __launch_bounds__(256) void u_mfma(
    const unsigned short* __restrict__ yh, const unsigned short* __restrict__ yl,
    const float* __restrict__ nys,
    const unsigned short* __restrict__ xh, const unsigned short* __restrict__ xl,
    const float* __restrict__ nxs,
    const float* __restrict__ bG, float* __restrict__ aG,
    float* __restrict__ errBlk, const int* __restrict__ doneFl, int it)
{
  if (it > 0 && doneFl[it - 1]) return;   // frozen: a, errBlk untouched

  const int n     = blockIdx.x >> 5;
  const int itile = blockIdx.x & 31;
  const int tid   = threadIdx.x;
  const int l     = tid & 63;
  const int w     = tid >> 6;

  __shared__ float bt[PP];
  __shared__ float mred[4][32];
  __shared__ float sred[4][32];

  {
    float4 nv = *(const float4*)(nys + n * PP + tid * 4);
    float4 b4 = make_float4(0.f, 0.f, 0.f, 0.f);
    if (it > 0) b4 = *(const float4*)(bG + n * PP + tid * 4);
    bt[tid * 4 + 0] = b4.x - nv.x; bt[tid * 4 + 1] = b4.y - nv.y;
    bt[tid * 4 + 2] = b4.z - nv.z; bt[tid * 4 + 3] = b4.w - nv.w;
  }
  __syncthreads();

  // x fragments (output side), resident across both sweeps
  const size_t brow = ((size_t)(n * PP + itile * 32 + (l & 31))) * DD;
  const int ko = 8 * (l >> 5);
  bf16x8 Bh0 = *(const bf16x8*)(xh + brow + 0 * 16 + ko);
  bf16x8 Bh1 = *(const bf16x8*)(xh + brow + 1 * 16 + ko);
  bf16x8 Bh2 = *(const bf16x8*)(xh + brow + 2 * 16 + ko);
  bf16x8 Bh3 = *(const bf16x8*)(xh + brow + 3 * 16 + ko);
  bf16x8 Bl0 = *(const bf16x8*)(xl + brow + 0 * 16 + ko);
  bf16x8 Bl1 = *(const bf16x8*)(xl + brow + 1 * 16 + ko);
  bf16x8 Bl2 = *(const bf16x8*)(xl + brow + 2 * 16 + ko);
  bf16x8 Bl3 = *(const bf16x8*)(xl + brow + 3 * 16 + ko);

  // ---- sweep 1: per-lane max over this wave's 256 j's ----
  float M = -INFINITY;
  for (int jt = 0; jt < 8; ++jt) {
    const int jrow0 = w * 256 + jt * 32;
    const size_t arow = ((size_t)(n * PP + jrow0 + (l & 31))) * DD;
    bf16x8 Ah0 = *(const bf16x8*)(yh + arow + 0 * 16 + ko);
    bf16x8 Ah1 = *(const bf16x8*)(yh + arow + 1 * 16 + ko);
    bf16x8 Ah2 = *(const bf16x8*)(yh + arow + 2 * 16 + ko);
    bf16x8 Ah3 = *(const bf16x8*)(yh + arow + 3 * 16 + ko);
    bf16x8 Al0 = *(const bf16x8*)(yl + arow + 0 * 16 + ko);
    bf16x8 Al1 = *(const bf16x8*)(yl + arow + 1 * 16 + ko);
    bf16x8 Al2 = *(const bf16x8*)(yl + arow + 2 * 16 + ko);
    bf16x8 Al3 = *(const bf16x8*)(yl + arow + 3 * 16 + ko);

    f32x16 acc;
    #pragma unroll
    for (int z = 0; z < 16; ++z) acc[z] = 0.f;
    acc = __builtin_amdgcn_mfma_f32_32x32x16_bf16(Ah0, Bh0, acc, 0, 0, 0);
    acc = __builtin_amdgcn_mfma_f32_32x32x16_bf16(Ah1, Bh1, acc, 0, 0, 0);
    acc = __builtin_amdgcn_mfma_f32_32x32x16_bf16(Ah2, Bh2, acc, 0, 0, 0);
    acc = __builtin_amdgcn_mfma_f32_32x32x16_bf16(Ah3, Bh3, acc, 0, 0, 0);
    acc = __builtin_amdgcn_mfma_f32_32x32x16_bf16(Ah0, Bl0, acc, 0, 0, 0);
    acc = __builtin_amdgcn_mfma_f32_32x32x16_bf16(Ah1, Bl1, acc, 0, 0, 0);
    acc = __builtin_amdgcn_mfma_f32_32x32x16_bf16(Ah2, Bl2, acc, 0, 0, 0);
    acc = __builtin_amdgcn_mfma_f32_32x32x16_bf16(Ah3, Bl3, acc, 0, 0, 0);
    acc = __builtin_amdgcn_mfma_f32_32x32x16_bf16(Al0, Bh0, acc, 0, 0, 0);
    acc = __builtin_amdgcn_mfma_f32_32x32x16_bf16(Al1, Bh1, acc, 0, 0, 0);
    acc = __builtin_amdgcn_mfma_f32_32x32x16_bf16(Al2, Bh2, acc, 0, 0, 0);
    acc = __builtin_amdgcn_mfma_f32_32x32x16_bf16(Al3, Bh3, acc, 0, 0, 0);

    const int jb = jrow0 + 4 * (l >> 5);
    #pragma unroll
    for (int r = 0; r < 16; ++r)
      M = fmaxf(M, fmaf(SCALE_G, acc[r], bt[jb + (r & 3) + 8 * (r >> 2)]));
  }
  M = fmaxf(M, __shfl_xor(M, 32));
  if (l < 32) mred[w][l] = M;
  __syncthreads();

  const int c = l & 31;
  const float Mf = fmaxf(fmaxf(mred[0][c], mred[1][c]),
                         fmaxf(mred[2][c], mred[3][c]));

  // ---- sweep 2: exp-sum against fixed Mf (recompute MFMA) ----
  float S = 0.f;
  for (int jt = 0; jt < 8; ++jt) {
    const int jrow0 = w * 256 + jt * 32;
    const size_t arow = ((size_t)(n * PP + jrow0 + (l & 31))) * DD;
    bf16x8 Ah0 = *(const bf16x8*)(yh + arow + 0 * 16 + ko);
    bf16x8 Ah1 = *(const bf16x8*)(yh + arow + 1 * 16 + ko);
    bf16x8 Ah2 = *(const bf16x8*)(yh + arow + 2 * 16 + ko);
    bf16x8 Ah3 = *(const bf16x8*)(yh + arow + 3 * 16 + ko);
    bf16x8 Al0 = *(const bf16x8*)(yl + arow + 0 * 16 + ko);
    bf16x8 Al1 = *(const bf16x8*)(yl + arow + 1 * 16 + ko);
    bf16x8 Al2 = *(const bf16x8*)(yl + arow + 2 * 16 + ko);
    bf16x8 Al3 = *(const bf16x8*)(yl + arow + 3 * 16 + ko);

    f32x16 acc;
    #pragma unroll
    for (int z = 0; z < 16; ++z) acc[z] = 0.f;
    acc = __builtin_amdgcn_mfma_f32_32x32x16_bf16(Ah0, Bh0, acc, 0, 0, 0);
    acc = __builtin_amdgcn_mfma_f32_32x32x16_bf16(Ah1, Bh1, acc, 0, 0, 0);
    acc = __builtin_amdgcn_mfma_f32_32x32x16_bf16(Ah2, Bh2, acc, 0, 0, 0);
    acc = __builtin_amdgcn_mfma_f32_32x32x16_bf16(Ah3, Bh3, acc, 0, 0, 0);
    acc = __builtin_amdgcn_mfma_f32_32x32x16_bf16(Ah0, Bl0, acc, 0, 0, 0);
    acc = __builtin_amdgcn_mfma_f32_32x32x16_bf16(Ah1, Bl1, acc, 0, 0, 0);
    acc = __builtin_amdgcn_mfma_f32_32x32x16_bf16(Ah2, Bl2, acc, 0, 0, 0);
    acc = __builtin_amdgcn_mfma_f32_32x32x16_bf16(Ah3, Bl3, acc, 0, 0, 0);
    acc = __builtin_amdgcn_mfma_f32_32x32x16_bf16(Al0, Bh0, acc, 0, 0, 0);
    acc = __builtin_amdgcn_mfma_f32_32x32x16_bf16(Al1, Bh1, acc, 0, 0, 0);
    acc = __builtin_amdgcn_mfma_f32_32x32x16_bf16(Al2, Bh2, acc, 0, 0, 0);
    acc = __builtin_amdgcn_mfma_f32_32x32x16_bf16(Al3, Bh3, acc, 0, 0, 0);

    const int jb = jrow0 + 4 * (l >> 5);
    #pragma unroll
    for (int r = 0; r < 16; ++r)
      S += exp2f((fmaf(SCALE_G, acc[r], bt[jb + (r & 3) + 8 * (r >> 2)]) - Mf) * LOG2E);
  }
  S += __shfl_xor(S, 32);
  if (l < 32) sred[w][l] = S;
  __syncthreads();

  if (tid < 32) {
    float Sf = sred[0][tid] + sred[1][tid] + sred[2][tid] + sred[3][tid];
    float Mc = fmaxf(fmaxf(mred[0][tid], mred[1][tid]),
                     fmaxf(mred[2][tid], mred[3][tid]));
    const int gi = n * PP + itile * 32 + tid;
    float newv = LOG_MU + nxs[gi] - (Mc + logf(Sf));
    float aOld = (it == 0) ? 0.f : aG[gi];
    aG[gi] = newv;
    float dErr = fabsf(newv - aOld);
    dErr += __shfl_xor(dErr, 1);
    dErr += __shfl_xor(dErr, 2);
    dErr += __shfl_xor(dErr, 4);
    dErr += __shfl_xor(dErr, 8);
    dErr += __shfl_xor(dErr, 16);
    if (tid == 0) errBlk[blockIdx.x] = dErr;
  }
}

// ---------------------------------------------------------------------------
// v_stripe (round-1 v_kernel, HW-proven; adapted: doneFl convention +
// errBlk[512] reduce): b_j = LOG_MU - lse_i(a_i - Cs_ij). 2-pass column
// stripes, 512 blocks = 16 n x 32 stripes of 32 cols.
// ---------------------------------------------------------------------------
__global__ __launch_bounds__(256) void v_stripe(
    const float* __restrict__ Cs, const float* __restrict__ aG,
    float* __restrict__ bG, const float* __restrict__ errBlk,
    int* __restrict__ doneFl, int it)
{
  if (it > 0 && doneFl[it - 1]) {
    if (blockIdx.x == 0 && threadIdx.x == 0) doneFl[it] = 1;
    return;
  }
  __shared__ float as[PP];
  __shared__ float red[8][33];

  const int n  = blockIdx.x >> 5;
  const int jt = blockIdx.x & 31;
  const float* an = aG + n * PP;
  for (int t = threadIdx.x; t < PP; t += 256) as[t] = an[t];
  __syncthreads();

  const int tx = threadIdx.x & 31;
  const int ty = threadIdx.x >> 5;
  const float* cb = Cs + (size_t)n * PP * PP + jt * 32 + tx;

  float m = -INFINITY;
  #pragma unroll 8
  for (int i = ty; i < PP; i += 8)
    m = fmaxf(m, as[i] - cb[(size_t)i * PP]);

  red[ty][tx] = m;
  __syncthreads();
  if (ty == 0) {
    #pragma unroll
    for (int k = 1; k < 8; ++k) m = fmaxf(m, red[k][tx]);
    red[0][tx] = m;
  }
  __syncthreads();
  m = red[0][tx];

  float s = 0.f;
  #pragma unroll 8
  for (int i = ty; i < PP; i += 8)
    s += exp2f((as[i] - cb[(size_t)i * PP] - m) * LOG2E);

  __syncthreads();
  red[ty][tx] = s;
  __syncthreads();
  if (ty == 0) {
    #pragma unroll
    for (int k = 1; k < 8; ++k) s += red[k][tx];
    bG[n * PP + jt * 32 + tx] = LOG_MU - (m + logf(s));
  }

  // convergence: fixed-order reduce of errBlk[512] -> doneFl[it]
  if (blockIdx.x == 0) {
    __syncthreads();
    float loc = errBlk[threadIdx.x] + errBlk[threadIdx.x + 256];
    #pragma unroll
    for (int mk = 32; mk; mk >>= 1) loc += __shfl_xor(loc, mk);
    if ((threadIdx.x & 63) == 0) red[0][threadIdx.x >> 6] = loc;
    __syncthreads();
    if (threadIdx.x == 0) {
      float tot = red[0][0] + red[0][1] + red[0][2] + red[0][3];
      doneFl[it] = (tot * (EPSV / (float)NB) < THRESHV) ? 1 : 0;
    }
  }
}

// ---------------------------------------------------------------------------
// pi = exp(a_i + b_j - Cs_ij), in place over Cs (d_out). (validated)
// ---------------------------------------------------------------------------
__global__ __launch_bounds__(256) void pi_kernel(
    float* __restrict__ Cs, const float* __restrict__ a, const float* __restrict__ b)
{
  const int lane = threadIdx.x & 63;
  const int row  = (blockIdx.x << 2) + (threadIdx.x >> 6);
  const int n    = row >> 10;
  const float ai = a[row];
  float* crow = Cs + (size_t)row * PP;
  const float* bn = b + n * PP;
  #pragma unroll
  for (int kk = 0; kk < 4; ++kk) {
    float4 c4 = *(const float4*)(crow + lane * 4 + kk * 256);
    float4 b4 = *(const float4*)(bn   + lane * 4 + kk * 256);
    float4 r;
    r.x = exp2f((ai + b4.x - c4.x) * LOG2E);
    r.y = exp2f((ai + b4.y - c4.y) * LOG2E);
    r.z = exp2f((ai + b4.z - c4.z) * LOG2E);
    r.w = exp2f((ai + b4.w - c4.w) * LOG2E);
    *(float4*)(crow + lane * 4 + kk * 256) = r;
  }
}

extern "C" void kernel_launch(void* const* d_in, const int* in_sizes, int n_in,
                              void* d_out, int out_size, void* d_ws, size_t ws_size,
                              hipStream_t stream)
{
  const float* y = (const float*)d_in[0];   // setup_inputs order: y first
  const float* x = (const float*)d_in[1];

  float* Cs = (float*)d_out;                 // Cs, then pi in place

  const size_t NE = (size_t)NB * PP * DD;    // 1,048,576 elems per split array
  unsigned short* xh = (unsigned short*)d_ws;
  unsigned short* xl = xh + NE;
  unsigned short* yh = xl + NE;
  unsigned short* yl = yh + NE;
  float* nxs    = (float*)(yl + NE);         // 16K floats
  float* nys    = nxs + NB * PP;             // 16K
  float* aG     = nys + NB * PP;             // 16K
  float* bG     = aG + NB * PP;              // 16K
  float* errBlk = bG + NB * PP;              // 512 floats
  int*   doneFl = (int*)(errBlk + 512);      // MAX_ITER ints

  prep_kernel<<<1024, 256, 0, stream>>>(x, y, xh, xl, yh, yl, nxs, nys);
  compute_c_mfma<<<4096, 256, 0, stream>>>(xh, xl, nxs, yh, yl, nys, Cs);
  for (int it = 0; it < MAX_ITER; ++it) {
    u_mfma<<<512, 256, 0, stream>>>(yh, yl, nys, xh, xl, nxs,
                                    bG, aG, errBlk, doneFl, it);
    v_stripe<<<512, 256, 0, stream>>>(Cs, aG, bG, errBlk, doneFl, it);
  }
  pi_kernel<<<NB * PP / 4, 256, 0, stream>>>(Cs, aG, bG);
}

// Round 11
// 716.703 us; speedup vs baseline: 1.1005x; 1.1005x over previous
//
#include <hip/hip_runtime.h>
#include <math.h>

#define NB 16
#define PP 1024
#define DD 64
#define MAX_ITER 10

constexpr float EPSV    = 0.1f;
constexpr float SCALE_G = 20.0f;     // 2/eps
constexpr float LOG2E   = 1.44269504088896340736f;
constexpr float LOG_MU  = -6.93146156597137f;   // log(1/1024 + 1e-8)
constexpr float THRESHV = 0.1f;

typedef short bf16x8 __attribute__((ext_vector_type(8)));
typedef float f32x16 __attribute__((ext_vector_type(16)));

__device__ __forceinline__ unsigned short f2bf(float f) {
  unsigned int u = __float_as_uint(f);
  return (unsigned short)((u + 0x7FFFu + ((u >> 16) & 1u)) >> 16);   // RNE
}
__device__ __forceinline__ float bf2f(unsigned short h) {
  return __uint_as_float(((unsigned int)h) << 16);
}

// ---------------------------------------------------------------------------
// Prep (validated r8): bf16 hi/lo split + scaled row norms 10*|r|^2.
// ---------------------------------------------------------------------------
__global__ __launch_bounds__(256) void prep_kernel(
    const float* __restrict__ x, const float* __restrict__ y,
    unsigned short* __restrict__ xh, unsigned short* __restrict__ xl,
    unsigned short* __restrict__ yh, unsigned short* __restrict__ yl,
    float* __restrict__ nxs, float* __restrict__ nys)
{
  const int sel = blockIdx.x >> 9;
  const int row = (blockIdx.x & 511) * 32 + (threadIdx.x >> 3);
  const int q   = threadIdx.x & 7;

  const float* src = sel ? y : x;
  unsigned short* H = sel ? yh : xh;
  unsigned short* L = sel ? yl : xl;
  float* N          = sel ? nys : nxs;

  const float* p = src + (size_t)row * DD + q * 8;
  float4 v0 = *(const float4*)(p);
  float4 v1 = *(const float4*)(p + 4);

  float f[8] = {v0.x, v0.y, v0.z, v0.w, v1.x, v1.y, v1.z, v1.w};
  float nrm = 0.f;
  unsigned short hb[8], lb[8];
  #pragma unroll
  for (int k = 0; k < 8; ++k) {
    nrm = fmaf(f[k], f[k], nrm);
    unsigned short h = f2bf(f[k]);
    float res = f[k] - bf2f(h);
    hb[k] = h; lb[k] = f2bf(res);
  }
  nrm += __shfl_xor(nrm, 1);
  nrm += __shfl_xor(nrm, 2);
  nrm += __shfl_xor(nrm, 4);
  if (q == 0) N[row] = 10.0f * nrm;

  uint4 ho, lo;
  ho.x = hb[0] | ((unsigned)hb[1] << 16); ho.y = hb[2] | ((unsigned)hb[3] << 16);
  ho.z = hb[4] | ((unsigned)hb[5] << 16); ho.w = hb[6] | ((unsigned)hb[7] << 16);
  lo.x = lb[0] | ((unsigned)lb[1] << 16); lo.y = lb[2] | ((unsigned)lb[3] << 16);
  lo.z = lb[4] | ((unsigned)lb[5] << 16); lo.w = lb[6] | ((unsigned)lb[7] << 16);
  *(uint4*)(H + (size_t)row * DD + q * 8) = ho;
  *(uint4*)(L + (size_t)row * DD + q * 8) = lo;
}

// ---------------------------------------------------------------------------
// Cs = nxs_i + nys_j - 20*<x_i,y_j> via split-bf16 MFMA (validated r8).
// ---------------------------------------------------------------------------
__global__ __launch_bounds__(256) void compute_c_mfma(
    const unsigned short* __restrict__ xh, const unsigned short* __restrict__ xl,
    const float* __restrict__ nxs,
    const unsigned short* __restrict__ yh, const unsigned short* __restrict__ yl,
    const float* __restrict__ nys,
    float* __restrict__ Cs)
{
  const int n   = blockIdx.x >> 8;
  const int ib  = (blockIdx.x >> 4) & 15;
  const int jb  = blockIdx.x & 15;
  const int tid = threadIdx.x;
  const int l   = tid & 63;
  const int w   = tid >> 6;
  const int ih  = w & 1, jh = w >> 1;

  __shared__ float nxv[64];
  if (tid < 64) nxv[tid] = nxs[n * PP + ib * 64 + tid];
  __syncthreads();

  const int jg  = n * PP + jb * 64 + 32 * jh + (l & 31);
  const float nyv = nys[jg];

  const int ko = 8 * (l >> 5);
  const size_t xrow = ((size_t)(n * PP + ib * 64 + 32 * ih + (l & 31))) * DD;
  const size_t yrow = ((size_t)jg) * DD;

  bf16x8 Xh0 = *(const bf16x8*)(xh + xrow + 0 * 16 + ko);
  bf16x8 Xh1 = *(const bf16x8*)(xh + xrow + 1 * 16 + ko);
  bf16x8 Xh2 = *(const bf16x8*)(xh + xrow + 2 * 16 + ko);
  bf16x8 Xh3 = *(const bf16x8*)(xh + xrow + 3 * 16 + ko);
  bf16x8 Xl0 = *(const bf16x8*)(xl + xrow + 0 * 16 + ko);
  bf16x8 Xl1 = *(const bf16x8*)(xl + xrow + 1 * 16 + ko);
  bf16x8 Xl2 = *(const bf16x8*)(xl + xrow + 2 * 16 + ko);
  bf16x8 Xl3 = *(const bf16x8*)(xl + xrow + 3 * 16 + ko);
  bf16x8 Yh0 = *(const bf16x8*)(yh + yrow + 0 * 16 + ko);
  bf16x8 Yh1 = *(const bf16x8*)(yh + yrow + 1 * 16 + ko);
  bf16x8 Yh2 = *(const bf16x8*)(yh + yrow + 2 * 16 + ko);
  bf16x8 Yh3 = *(const bf16x8*)(yh + yrow + 3 * 16 + ko);
  bf16x8 Yl0 = *(const bf16x8*)(yl + yrow + 0 * 16 + ko);
  bf16x8 Yl1 = *(const bf16x8*)(yl + yrow + 1 * 16 + ko);
  bf16x8 Yl2 = *(const bf16x8*)(yl + yrow + 2 * 16 + ko);
  bf16x8 Yl3 = *(const bf16x8*)(yl + yrow + 3 * 16 + ko);

  f32x16 acc;
  #pragma unroll
  for (int z = 0; z < 16; ++z) acc[z] = 0.f;
  acc = __builtin_amdgcn_mfma_f32_32x32x16_bf16(Xh0, Yh0, acc, 0, 0, 0);
  acc = __builtin_amdgcn_mfma_f32_32x32x16_bf16(Xh1, Yh1, acc, 0, 0, 0);
  acc = __builtin_amdgcn_mfma_f32_32x32x16_bf16(Xh2, Yh2, acc, 0, 0, 0);
  acc = __builtin_amdgcn_mfma_f32_32x32x16_bf16(Xh3, Yh3, acc, 0, 0, 0);
  acc = __builtin_amdgcn_mfma_f32_32x32x16_bf16(Xh0, Yl0, acc, 0, 0, 0);
  acc = __builtin_amdgcn_mfma_f32_32x32x16_bf16(Xh1, Yl1, acc, 0, 0, 0);
  acc = __builtin_amdgcn_mfma_f32_32x32x16_bf16(Xh2, Yl2, acc, 0, 0, 0);
  acc = __builtin_amdgcn_mfma_f32_32x32x16_bf16(Xh3, Yl3, acc, 0, 0, 0);
  acc = __builtin_amdgcn_mfma_f32_32x32x16_bf16(Xl0, Yh0, acc, 0, 0, 0);
  acc = __builtin_amdgcn_mfma_f32_32x32x16_bf16(Xl1, Yh1, acc, 0, 0, 0);
  acc = __builtin_amdgcn_mfma_f32_32x32x16_bf16(Xl2, Yh2, acc, 0, 0, 0);
  acc = __builtin_amdgcn_mfma_f32_32x32x16_bf16(Xl3, Yh3, acc, 0, 0, 0);

  const int irb  = 32 * ih + 4 * (l >> 5);
  const int jcol = jb * 64 + 32 * jh + (l & 31);
  #pragma unroll
  for (int r = 0; r < 16; ++r) {
    const int irel = irb + (r & 3) + 8 * (r >> 2);
    const size_t off = ((size_t)(n * PP + ib * 64 + irel)) * PP + jcol;
    Cs[off] = nxv[irel] + nyv - SCALE_G * acc[r];
  }
}

// ---------------------------------------------------------------------------
// u_mfma (VALIDATED r10): a_i = LOG_MU + nxs_i - lse_j(bt_j + 20<y_j, x_i>),
// bt_j = b_j - nys_j. Two-sweep (block max, then exp-sum). Grid 512.
// ---------------------------------------------------------------------------
__global__ __launch_bounds__(256) void u_mfma(
    const unsigned short* __restrict__ yh, const unsigned short* __restrict__ yl,
    const float* __restrict__ nys,
    const unsigned short* __restrict__ xh, const unsigned short* __restrict__ xl,
    const float* __restrict__ nxs,
    const float* __restrict__ bG, float* __restrict__ aG,
    float* __restrict__ errBlk, const int* __restrict__ doneFl, int it)
{
  if (it > 0 && doneFl[it - 1]) return;   // frozen: a, errBlk untouched

  const int n     = blockIdx.x >> 5;
  const int itile = blockIdx.x & 31;
  const int tid   = threadIdx.x;
  const int l     = tid & 63;
  const int w     = tid >> 6;

  __shared__ float bt[PP];
  __shared__ float mred[4][32];
  __shared__ float sred[4][32];

  {
    float4 nv = *(const float4*)(nys + n * PP + tid * 4);
    float4 b4 = make_float4(0.f, 0.f, 0.f, 0.f);
    if (it > 0) b4 = *(const float4*)(bG + n * PP + tid * 4);
    bt[tid * 4 + 0] = b4.x - nv.x; bt[tid * 4 + 1] = b4.y - nv.y;
    bt[tid * 4 + 2] = b4.z - nv.z; bt[tid * 4 + 3] = b4.w - nv.w;
  }
  __syncthreads();

  const size_t brow = ((size_t)(n * PP + itile * 32 + (l & 31))) * DD;
  const int ko = 8 * (l >> 5);
  bf16x8 Bh0 = *(const bf16x8*)(xh + brow + 0 * 16 + ko);
  bf16x8 Bh1 = *(const bf16x8*)(xh + brow + 1 * 16 + ko);
  bf16x8 Bh2 = *(const bf16x8*)(xh + brow + 2 * 16 + ko);
  bf16x8 Bh3 = *(const bf16x8*)(xh + brow + 3 * 16 + ko);
  bf16x8 Bl0 = *(const bf16x8*)(xl + brow + 0 * 16 + ko);
  bf16x8 Bl1 = *(const bf16x8*)(xl + brow + 1 * 16 + ko);
  bf16x8 Bl2 = *(const bf16x8*)(xl + brow + 2 * 16 + ko);
  bf16x8 Bl3 = *(const bf16x8*)(xl + brow + 3 * 16 + ko);

  float M = -INFINITY;
  for (int jt = 0; jt < 8; ++jt) {
    const int jrow0 = w * 256 + jt * 32;
    const size_t arow = ((size_t)(n * PP + jrow0 + (l & 31))) * DD;
    bf16x8 Ah0 = *(const bf16x8*)(yh + arow + 0 * 16 + ko);
    bf16x8 Ah1 = *(const bf16x8*)(yh + arow + 1 * 16 + ko);
    bf16x8 Ah2 = *(const bf16x8*)(yh + arow + 2 * 16 + ko);
    bf16x8 Ah3 = *(const bf16x8*)(yh + arow + 3 * 16 + ko);
    bf16x8 Al0 = *(const bf16x8*)(yl + arow + 0 * 16 + ko);
    bf16x8 Al1 = *(const bf16x8*)(yl + arow + 1 * 16 + ko);
    bf16x8 Al2 = *(const bf16x8*)(yl + arow + 2 * 16 + ko);
    bf16x8 Al3 = *(const bf16x8*)(yl + arow + 3 * 16 + ko);

    f32x16 acc;
    #pragma unroll
    for (int z = 0; z < 16; ++z) acc[z] = 0.f;
    acc = __builtin_amdgcn_mfma_f32_32x32x16_bf16(Ah0, Bh0, acc, 0, 0, 0);
    acc = __builtin_amdgcn_mfma_f32_32x32x16_bf16(Ah1, Bh1, acc, 0, 0, 0);
    acc = __builtin_amdgcn_mfma_f32_32x32x16_bf16(Ah2, Bh2, acc, 0, 0, 0);
    acc = __builtin_amdgcn_mfma_f32_32x32x16_bf16(Ah3, Bh3, acc, 0, 0, 0);
    acc = __builtin_amdgcn_mfma_f32_32x32x16_bf16(Ah0, Bl0, acc, 0, 0, 0);
    acc = __builtin_amdgcn_mfma_f32_32x32x16_bf16(Ah1, Bl1, acc, 0, 0, 0);
    acc = __builtin_amdgcn_mfma_f32_32x32x16_bf16(Ah2, Bl2, acc, 0, 0, 0);
    acc = __builtin_amdgcn_mfma_f32_32x32x16_bf16(Ah3, Bl3, acc, 0, 0, 0);
    acc = __builtin_amdgcn_mfma_f32_32x32x16_bf16(Al0, Bh0, acc, 0, 0, 0);
    acc = __builtin_amdgcn_mfma_f32_32x32x16_bf16(Al1, Bh1, acc, 0, 0, 0);
    acc = __builtin_amdgcn_mfma_f32_32x32x16_bf16(Al2, Bh2, acc, 0, 0, 0);
    acc = __builtin_amdgcn_mfma_f32_32x32x16_bf16(Al3, Bh3, acc, 0, 0, 0);

    const int jb = jrow0 + 4 * (l >> 5);
    #pragma unroll
    for (int r = 0; r < 16; ++r)
      M = fmaxf(M, fmaf(SCALE_G, acc[r], bt[jb + (r & 3) + 8 * (r >> 2)]));
  }
  M = fmaxf(M, __shfl_xor(M, 32));
  if (l < 32) mred[w][l] = M;
  __syncthreads();

  const int c = l & 31;
  const float Mf = fmaxf(fmaxf(mred[0][c], mred[1][c]),
                         fmaxf(mred[2][c], mred[3][c]));

  float S = 0.f;
  for (int jt = 0; jt < 8; ++jt) {
    const int jrow0 = w * 256 + jt * 32;
    const size_t arow = ((size_t)(n * PP + jrow0 + (l & 31))) * DD;
    bf16x8 Ah0 = *(const bf16x8*)(yh + arow + 0 * 16 + ko);
    bf16x8 Ah1 = *(const bf16x8*)(yh + arow + 1 * 16 + ko);
    bf16x8 Ah2 = *(const bf16x8*)(yh + arow + 2 * 16 + ko);
    bf16x8 Ah3 = *(const bf16x8*)(yh + arow + 3 * 16 + ko);
    bf16x8 Al0 = *(const bf16x8*)(yl + arow + 0 * 16 + ko);
    bf16x8 Al1 = *(const bf16x8*)(yl + arow + 1 * 16 + ko);
    bf16x8 Al2 = *(const bf16x8*)(yl + arow + 2 * 16 + ko);
    bf16x8 Al3 = *(const bf16x8*)(yl + arow + 3 * 16 + ko);

    f32x16 acc;
    #pragma unroll
    for (int z = 0; z < 16; ++z) acc[z] = 0.f;
    acc = __builtin_amdgcn_mfma_f32_32x32x16_bf16(Ah0, Bh0, acc, 0, 0, 0);
    acc = __builtin_amdgcn_mfma_f32_32x32x16_bf16(Ah1, Bh1, acc, 0, 0, 0);
    acc = __builtin_amdgcn_mfma_f32_32x32x16_bf16(Ah2, Bh2, acc, 0, 0, 0);
    acc = __builtin_amdgcn_mfma_f32_32x32x16_bf16(Ah3, Bh3, acc, 0, 0, 0);
    acc = __builtin_amdgcn_mfma_f32_32x32x16_bf16(Ah0, Bl0, acc, 0, 0, 0);
    acc = __builtin_amdgcn_mfma_f32_32x32x16_bf16(Ah1, Bl1, acc, 0, 0, 0);
    acc = __builtin_amdgcn_mfma_f32_32x32x16_bf16(Ah2, Bl2, acc, 0, 0, 0);
    acc = __builtin_amdgcn_mfma_f32_32x32x16_bf16(Ah3, Bl3, acc, 0, 0, 0);
    acc = __builtin_amdgcn_mfma_f32_32x32x16_bf16(Al0, Bh0, acc, 0, 0, 0);
    acc = __builtin_amdgcn_mfma_f32_32x32x16_bf16(Al1, Bh1, acc, 0, 0, 0);
    acc = __builtin_amdgcn_mfma_f32_32x32x16_bf16(Al2, Bh2, acc, 0, 0, 0);
    acc = __builtin_amdgcn_mfma_f32_32x32x16_bf16(Al3, Bh3, acc, 0, 0, 0);

    const int jb = jrow0 + 4 * (l >> 5);
    #pragma unroll
    for (int r = 0; r < 16; ++r)
      S += exp2f((fmaf(SCALE_G, acc[r], bt[jb + (r & 3) + 8 * (r >> 2)]) - Mf) * LOG2E);
  }
  S += __shfl_xor(S, 32);
  if (l < 32) sred[w][l] = S;
  __syncthreads();

  if (tid < 32) {
    float Sf = sred[0][tid] + sred[1][tid] + sred[2][tid] + sred[3][tid];
    float Mc = fmaxf(fmaxf(mred[0][tid], mred[1][tid]),
                     fmaxf(mred[2][tid], mred[3][tid]));
    const int gi = n * PP + itile * 32 + tid;
    float newv = LOG_MU + nxs[gi] - (Mc + logf(Sf));
    float aOld = (it == 0) ? 0.f : aG[gi];
    aG[gi] = newv;
    float dErr = fabsf(newv - aOld);
    dErr += __shfl_xor(dErr, 1);
    dErr += __shfl_xor(dErr, 2);
    dErr += __shfl_xor(dErr, 4);
    dErr += __shfl_xor(dErr, 8);
    dErr += __shfl_xor(dErr, 16);
    if (tid == 0) errBlk[blockIdx.x] = dErr;
  }
}

// ---------------------------------------------------------------------------
// v_mfma (NEW, mirror of validated u_mfma): b_j = LOG_MU + nys_j -
// lse_i(at_i + 20<x_i, y_j>), at_i = a_i - nxs_i. Two-sweep. Grid 512.
// Also: freeze-propagation + convergence reduce (was in v_stripe).
// ---------------------------------------------------------------------------
__global__ __launch_bounds__(256) void v_mfma(
    const unsigned short* __restrict__ xh, const unsigned short* __restrict__ xl,
    const float* __restrict__ nxs,
    const unsigned short* __restrict__ yh, const unsigned short* __restrict__ yl,
    const float* __restrict__ nys,
    const float* __restrict__ aG, float* __restrict__ bG,
    const float* __restrict__ errBlk, int* __restrict__ doneFl, int it)
{
  const int tid = threadIdx.x;
  if (it > 0 && doneFl[it - 1]) {
    if (blockIdx.x == 0 && tid == 0) doneFl[it] = 1;   // stays converged
    return;
  }
  const int n     = blockIdx.x >> 5;
  const int jtile = blockIdx.x & 31;
  const int l     = tid & 63;
  const int w     = tid >> 6;

  __shared__ float at[PP];
  __shared__ float mred[4][32];
  __shared__ float sred[4][32];
  __shared__ float red4[4];

  {
    float4 nv = *(const float4*)(nxs + n * PP + tid * 4);
    float4 a4 = *(const float4*)(aG + n * PP + tid * 4);   // a is fresh (u ran)
    at[tid * 4 + 0] = a4.x - nv.x; at[tid * 4 + 1] = a4.y - nv.y;
    at[tid * 4 + 2] = a4.z - nv.z; at[tid * 4 + 3] = a4.w - nv.w;
  }
  __syncthreads();

  // B fragments = y rows (output side)
  const size_t brow = ((size_t)(n * PP + jtile * 32 + (l & 31))) * DD;
  const int ko = 8 * (l >> 5);
  bf16x8 Bh0 = *(const bf16x8*)(yh + brow + 0 * 16 + ko);
  bf16x8 Bh1 = *(const bf16x8*)(yh + brow + 1 * 16 + ko);
  bf16x8 Bh2 = *(const bf16x8*)(yh + brow + 2 * 16 + ko);
  bf16x8 Bh3 = *(const bf16x8*)(yh + brow + 3 * 16 + ko);
  bf16x8 Bl0 = *(const bf16x8*)(yl + brow + 0 * 16 + ko);
  bf16x8 Bl1 = *(const bf16x8*)(yl + brow + 1 * 16 + ko);
  bf16x8 Bl2 = *(const bf16x8*)(yl + brow + 2 * 16 + ko);
  bf16x8 Bl3 = *(const bf16x8*)(yl + brow + 3 * 16 + ko);

  float M = -INFINITY;
  for (int jt = 0; jt < 8; ++jt) {
    const int irow0 = w * 256 + jt * 32;
    const size_t arow = ((size_t)(n * PP + irow0 + (l & 31))) * DD;
    bf16x8 Ah0 = *(const bf16x8*)(xh + arow + 0 * 16 + ko);
    bf16x8 Ah1 = *(const bf16x8*)(xh + arow + 1 * 16 + ko);
    bf16x8 Ah2 = *(const bf16x8*)(xh + arow + 2 * 16 + ko);
    bf16x8 Ah3 = *(const bf16x8*)(xh + arow + 3 * 16 + ko);
    bf16x8 Al0 = *(const bf16x8*)(xl + arow + 0 * 16 + ko);
    bf16x8 Al1 = *(const bf16x8*)(xl + arow + 1 * 16 + ko);
    bf16x8 Al2 = *(const bf16x8*)(xl + arow + 2 * 16 + ko);
    bf16x8 Al3 = *(const bf16x8*)(xl + arow + 3 * 16 + ko);

    f32x16 acc;
    #pragma unroll
    for (int z = 0; z < 16; ++z) acc[z] = 0.f;
    acc = __builtin_amdgcn_mfma_f32_32x32x16_bf16(Ah0, Bh0, acc, 0, 0, 0);
    acc = __builtin_amdgcn_mfma_f32_32x32x16_bf16(Ah1, Bh1, acc, 0, 0, 0);
    acc = __builtin_amdgcn_mfma_f32_32x32x16_bf16(Ah2, Bh2, acc, 0, 0, 0);
    acc = __builtin_amdgcn_mfma_f32_32x32x16_bf16(Ah3, Bh3, acc, 0, 0, 0);
    acc = __builtin_amdgcn_mfma_f32_32x32x16_bf16(Ah0, Bl0, acc, 0, 0, 0);
    acc = __builtin_amdgcn_mfma_f32_32x32x16_bf16(Ah1, Bl1, acc, 0, 0, 0);
    acc = __builtin_amdgcn_mfma_f32_32x32x16_bf16(Ah2, Bl2, acc, 0, 0, 0);
    acc = __builtin_amdgcn_mfma_f32_32x32x16_bf16(Ah3, Bl3, acc, 0, 0, 0);
    acc = __builtin_amdgcn_mfma_f32_32x32x16_bf16(Al0, Bh0, acc, 0, 0, 0);
    acc = __builtin_amdgcn_mfma_f32_32x32x16_bf16(Al1, Bh1, acc, 0, 0, 0);
    acc = __builtin_amdgcn_mfma_f32_32x32x16_bf16(Al2, Bh2, acc, 0, 0, 0);
    acc = __builtin_amdgcn_mfma_f32_32x32x16_bf16(Al3, Bh3, acc, 0, 0, 0);

    const int jb = irow0 + 4 * (l >> 5);
    #pragma unroll
    for (int r = 0; r < 16; ++r)
      M = fmaxf(M, fmaf(SCALE_G, acc[r], at[jb + (r & 3) + 8 * (r >> 2)]));
  }
  M = fmaxf(M, __shfl_xor(M, 32));
  if (l < 32) mred[w][l] = M;
  __syncthreads();

  const int c = l & 31;
  const float Mf = fmaxf(fmaxf(mred[0][c], mred[1][c]),
                         fmaxf(mred[2][c], mred[3][c]));

  float S = 0.f;
  for (int jt = 0; jt < 8; ++jt) {
    const int irow0 = w * 256 + jt * 32;
    const size_t arow = ((size_t)(n * PP + irow0 + (l & 31))) * DD;
    bf16x8 Ah0 = *(const bf16x8*)(xh + arow + 0 * 16 + ko);
    bf16x8 Ah1 = *(const bf16x8*)(xh + arow + 1 * 16 + ko);
    bf16x8 Ah2 = *(const bf16x8*)(xh + arow + 2 * 16 + ko);
    bf16x8 Ah3 = *(const bf16x8*)(xh + arow + 3 * 16 + ko);
    bf16x8 Al0 = *(const bf16x8*)(xl + arow + 0 * 16 + ko);
    bf16x8 Al1 = *(const bf16x8*)(xl + arow + 1 * 16 + ko);
    bf16x8 Al2 = *(const bf16x8*)(xl + arow + 2 * 16 + ko);
    bf16x8 Al3 = *(const bf16x8*)(xl + arow + 3 * 16 + ko);

    f32x16 acc;
    #pragma unroll
    for (int z = 0; z < 16; ++z) acc[z] = 0.f;
    acc = __builtin_amdgcn_mfma_f32_32x32x16_bf16(Ah0, Bh0, acc, 0, 0, 0);
    acc = __builtin_amdgcn_mfma_f32_32x32x16_bf16(Ah1, Bh1, acc, 0, 0, 0);
    acc = __builtin_amdgcn_mfma_f32_32x32x16_bf16(Ah2, Bh2, acc, 0, 0, 0);
    acc = __builtin_amdgcn_mfma_f32_32x32x16_bf16(Ah3, Bh3, acc, 0, 0, 0);
    acc = __builtin_amdgcn_mfma_f32_32x32x16_bf16(Ah0, Bl0, acc, 0, 0, 0);
    acc = __builtin_amdgcn_mfma_f32_32x32x16_bf16(Ah1, Bl1, acc, 0, 0, 0);
    acc = __builtin_amdgcn_mfma_f32_32x32x16_bf16(Ah2, Bl2, acc, 0, 0, 0);
    acc = __builtin_amdgcn_mfma_f32_32x32x16_bf16(Ah3, Bl3, acc, 0, 0, 0);
    acc = __builtin_amdgcn_mfma_f32_32x32x16_bf16(Al0, Bh0, acc, 0, 0, 0);
    acc = __builtin_amdgcn_mfma_f32_32x32x16_bf16(Al1, Bh1, acc, 0, 0, 0);
    acc = __builtin_amdgcn_mfma_f32_32x32x16_bf16(Al2, Bh2, acc, 0, 0, 0);
    acc = __builtin_amdgcn_mfma_f32_32x32x16_bf16(Al3, Bh3, acc, 0, 0, 0);

    const int jb = irow0 + 4 * (l >> 5);
    #pragma unroll
    for (int r = 0; r < 16; ++r)
      S += exp2f((fmaf(SCALE_G, acc[r], at[jb + (r & 3) + 8 * (r >> 2)]) - Mf) * LOG2E);
  }
  S += __shfl_xor(S, 32);
  if (l < 32) sred[w][l] = S;
  __syncthreads();

  if (tid < 32) {
    float Sf = sred[0][tid] + sred[1][tid] + sred[2][tid] + sred[3][tid];
    float Mc = fmaxf(fmaxf(mred[0][tid], mred[1][tid]),
                     fmaxf(mred[2][tid], mred[3][tid]));
    const int gi = n * PP + jtile * 32 + tid;
    bG[gi] = LOG_MU + nys[gi] - (Mc + logf(Sf));
  }

  // block 0: fixed-order reduce of errBlk[512] (written by this iter's u) -> doneFl
  if (blockIdx.x == 0) {
    __syncthreads();
    float loc = errBlk[tid] + errBlk[tid + 256];
    #pragma unroll
    for (int mk = 32; mk; mk >>= 1) loc += __shfl_xor(loc, mk);
    if (l == 0) red4[w] = loc;
    __syncthreads();
    if (tid == 0) {
      float tot = red4[0] + red4[1] + red4[2] + red4[3];
      doneFl[it] = (tot * (EPSV / (float)NB) < THRESHV) ? 1 : 0;
    }
  }
}

// ---------------------------------------------------------------------------
// pi = exp(a_i + b_j - Cs_ij), in place over Cs (d_out). (validated)
// ---------------------------------------------------------------------------
__global__ __launch_bounds__(256) void pi_kernel(
    float* __restrict__ Cs, const float* __restrict__ a, const float* __restrict__ b)
{
  const int lane = threadIdx.x & 63;
  const int row  = (blockIdx.x << 2) + (threadIdx.x >> 6);
  const int n    = row >> 10;
  const float ai = a[row];
  float* crow = Cs + (size_t)row * PP;
  const float* bn = b + n * PP;
  #pragma unroll
  for (int kk = 0; kk < 4; ++kk) {
    float4 c4 = *(const float4*)(crow + lane * 4 + kk * 256);
    float4 b4 = *(const float4*)(bn   + lane * 4 + kk * 256);
    float4 r;
    r.x = exp2f((ai + b4.x - c4.x) * LOG2E);
    r.y = exp2f((ai + b4.y - c4.y) * LOG2E);
    r.z = exp2f((ai + b4.z - c4.z) * LOG2E);
    r.w = exp2f((ai + b4.w - c4.w) * LOG2E);
    *(float4*)(crow + lane * 4 + kk * 256) = r;
  }
}

extern "C" void kernel_launch(void* const* d_in, const int* in_sizes, int n_in,
                              void* d_out, int out_size, void* d_ws, size_t ws_size,
                              hipStream_t stream)
{
  const float* y = (const float*)d_in[0];   // setup_inputs order: y first
  const float* x = (const float*)d_in[1];

  float* Cs = (float*)d_out;                 // Cs (epilogue only), then pi in place

  const size_t NE = (size_t)NB * PP * DD;    // 1,048,576 elems per split array
  unsigned short* xh = (unsigned short*)d_ws;
  unsigned short* xl = xh + NE;
  unsigned short* yh = xl + NE;
  unsigned short* yl = yh + NE;
  float* nxs    = (float*)(yl + NE);         // 16K floats
  float* nys    = nxs + NB * PP;             // 16K
  float* aG     = nys + NB * PP;             // 16K
  float* bG     = aG + NB * PP;              // 16K
  float* errBlk = bG + NB * PP;              // 512 floats
  int*   doneFl = (int*)(errBlk + 512);      // MAX_ITER ints

  prep_kernel<<<1024, 256, 0, stream>>>(x, y, xh, xl, yh, yl, nxs, nys);
  for (int it = 0; it < MAX_ITER; ++it) {
    u_mfma<<<512, 256, 0, stream>>>(yh, yl, nys, xh, xl, nxs,
                                    bG, aG, errBlk, doneFl, it);
    v_mfma<<<512, 256, 0, stream>>>(xh, xl, nxs, yh, yl, nys,
                                    aG, bG, errBlk, doneFl, it);
  }
  compute_c_mfma<<<4096, 256, 0, stream>>>(xh, xl, nxs, yh, yl, nys, Cs);
  pi_kernel<<<NB * PP / 4, 256, 0, stream>>>(Cs, aG, bG);
}